// Round 7
// baseline (297.373 us; speedup 1.0000x reference)
//
#include <hip/hip_runtime.h>

// AlignmentNet round 7: deform with 2-threads-per-pixel (halved serial load
// chains), 128-thread blocks for fine residency, pure global gathers
// (round-6 LDS window reverted). Branch-batched MFMA conv pipeline kept.

using bf16x8 = __attribute__((ext_vector_type(8))) short;
using u16x8  = __attribute__((ext_vector_type(8))) unsigned short;
using f32x4  = __attribute__((ext_vector_type(4))) float;

static constexpr int Hh = 128, Ww = 128, NB = 4, NPIX = Hh * Ww;
static constexpr int BB = 8;  // batch*branches

__device__ __forceinline__ unsigned short f2bf(float f) {
  unsigned u = __float_as_uint(f);
  u += 0x7fffu + ((u >> 16) & 1u);   // round-to-nearest-even
  return (unsigned short)(u >> 16);
}
__device__ __forceinline__ float bf2f(unsigned short h) {
  return __uint_as_float(((unsigned)h) << 16);
}

// ---------------------------------------------------------------------------
// Fused weight prep (blockIdx.y selects tensor).
// ---------------------------------------------------------------------------
struct PrepPtrs {
  const float* cw[5];
  unsigned short* cd[5];
  const float* dw[4];
  unsigned short* dd[4];
};

__global__ __launch_bounds__(256) void prep_all_kernel(PrepPtrs pp) {
  const int which = blockIdx.y;
  const int i = blockIdx.x * 256 + threadIdx.x;
  if (which == 0) {
    if (i >= 9 * 64 * 128) return;
    const int cin = 128, cop = 64;
    const int ci = i % cin, co = (i / cin) % cop, t = i / (cin * cop);
    pp.cd[0][i] = f2bf(pp.cw[0][((size_t)co * cin + ci) * 9 + t]);
  } else if (which <= 4) {
    if (i >= 9 * 80 * 64) return;
    const int cin = 64, cop = 80, co_real = 72;
    const int ci = i % cin, co = (i / cin) % cop, t = i / (cin * cop);
    float v = (co < co_real) ? pp.cw[which][((size_t)co * cin + ci) * 9 + t]
                             : 0.f;
    pp.cd[which][i] = f2bf(v);
  } else {
    if (i >= 4 * 5 * 16 * 32) return;
    const int kk = i & 31, o = (i >> 5) & 15, pair = (i >> 9) % 5;
    const int g = i / 2560;
    const int t = pair * 2 + (kk >> 4), c = kk & 15;
    float v = (t < 9) ? pp.dw[which - 5][(size_t)((g * 16 + o) * 16 + c) * 9 + t]
                      : 0.f;
    pp.dd[which - 5][i] = f2bf(v);
  }
}

// ---------------------------------------------------------------------------
// NCHW f32 -> group-split bf16: frefG [4][4][pix][16], fmovG [8][4][pix][16]
// ---------------------------------------------------------------------------
__global__ __launch_bounds__(256) void to_gs_kernel(
    const float* __restrict__ Fref, const float* __restrict__ Fm1,
    const float* __restrict__ Fm2, unsigned short* __restrict__ frefG,
    unsigned short* __restrict__ fmovG) {
  const int t = blockIdx.x * 256 + threadIdx.x;  // over BB*NPIX
  const int b2 = t >> 14, pix = t & (NPIX - 1);
  const float* fm = (b2 < 4 ? Fm1 : Fm2) + (size_t)(b2 & 3) * 64 * NPIX + pix;
  for (int c8 = 0; c8 < 8; ++c8) {
    u16x8 v;
#pragma unroll
    for (int j = 0; j < 8; ++j) v[j] = f2bf(fm[(size_t)(c8 * 8 + j) * NPIX]);
    *(u16x8*)(fmovG + ((size_t)(b2 * 4 + (c8 >> 1)) * NPIX + pix) * 16 +
              (c8 & 1) * 8) = v;
  }
  if (b2 < 4) {
    const float* fr = Fref + (size_t)b2 * 64 * NPIX + pix;
    for (int c8 = 0; c8 < 8; ++c8) {
      u16x8 v;
#pragma unroll
      for (int j = 0; j < 8; ++j) v[j] = f2bf(fr[(size_t)(c8 * 8 + j) * NPIX]);
      *(u16x8*)(frefG + ((size_t)(b2 * 4 + (c8 >> 1)) * NPIX + pix) * 16 +
                (c8 & 1) * 8) = v;
    }
  }
}

// ---------------------------------------------------------------------------
// MFMA conv 3x3 pad 1 (group-split inputs; see round 5).
// ---------------------------------------------------------------------------
template <int CIN, int COP, int CO_REAL, int OST, bool OUT_GS>
__global__ __launch_bounds__(512) void convmfma_kernel(
    const unsigned short* __restrict__ in0, int bmask0,
    const unsigned short* __restrict__ in1, int bmask1,
    const unsigned short* __restrict__ wT,   // [9][COP][CIN] bf16
    const float* __restrict__ biasP,         // [CO_REAL]
    unsigned short* __restrict__ out) {
  constexpr int COF = COP / 16;
  constexpr int NCH = CIN / 64;
  __shared__ unsigned short sA[9 * COP * 64];
  __shared__ unsigned short sB[324 * 64];

  const int tile = blockIdx.x, b = blockIdx.y;
  const int ty0 = (tile >> 3) << 4, tx0 = (tile & 7) << 4;
  const int tid = threadIdx.x;
  const int wv = tid >> 6, l = tid & 63;
  const int lm = l & 15, lq = l >> 4;

  f32x4 acc[COF][2];
#pragma unroll
  for (int cf = 0; cf < COF; ++cf)
#pragma unroll
    for (int pf = 0; pf < 2; ++pf) acc[cf][pf] = (f32x4){0.f, 0.f, 0.f, 0.f};

  const unsigned short* base0 = in0 + (size_t)(b & bmask0) * 4 * NPIX * 16;
  const unsigned short* base1 =
      (NCH > 1) ? in1 + (size_t)(b & bmask1) * 4 * NPIX * 16 : nullptr;

  for (int ch = 0; ch < NCH; ++ch) {
    const unsigned short* inB = (ch == 0) ? base0 : base1;
    for (int q = tid; q < 324 * 8; q += 512) {
      const int pix = q >> 3, ci8 = q & 7;
      const int r = pix / 18, c = pix - r * 18;
      const int gy = ty0 - 1 + r, gx = tx0 - 1 + c;
      u16x8 v;
      if (gy >= 0 && gy < Hh && gx >= 0 && gx < Ww) {
        v = *(const u16x8*)(inB + ((size_t)(ci8 >> 1) * NPIX + gy * Ww + gx) *
                                      16 + (ci8 & 1) * 8);
      } else {
#pragma unroll
        for (int j = 0; j < 8; ++j) v[j] = 0;
      }
      const int boff = pix * 128 + ((ci8 * 16) ^ ((pix & 7) << 4));
      *(u16x8*)((char*)sB + boff) = v;
    }
    for (int q = tid; q < 9 * COP * 8; q += 512) {
      const int ci8 = q & 7;
      const int co = (q >> 3) % COP;
      const int t = q / (8 * COP);
      u16x8 v = *(const u16x8*)(wT + (size_t)(t * COP + co) * CIN + ch * 64 +
                                ci8 * 8);
      const int aoff = (t * COP + co) * 128 + ((ci8 * 16) ^ ((co & 7) << 4));
      *(u16x8*)((char*)sA + aoff) = v;
    }
    __syncthreads();
    for (int t = 0; t < 9; ++t) {
      const int dy = t / 3, dx = t - dy * 3;
#pragma unroll
      for (int kc = 0; kc < 2; ++kc) {
        bf16x8 afr[COF];
#pragma unroll
        for (int cf = 0; cf < COF; ++cf) {
          const int co = cf * 16 + lm;
          const int aoff =
              (t * COP + co) * 128 + ((kc * 64 + lq * 16) ^ ((co & 7) << 4));
          afr[cf] = *(const bf16x8*)((const char*)sA + aoff);
        }
#pragma unroll
        for (int pf = 0; pf < 2; ++pf) {
          const int pix = wv * 32 + pf * 16 + lm;
          const int spix = ((pix >> 4) + dy) * 18 + (pix & 15) + dx;
          const int boff =
              spix * 128 + ((kc * 64 + lq * 16) ^ ((spix & 7) << 4));
          const bf16x8 bfr = *(const bf16x8*)((const char*)sB + boff);
#pragma unroll
          for (int cf = 0; cf < COF; ++cf)
            acc[cf][pf] = __builtin_amdgcn_mfma_f32_16x16x32_bf16(
                afr[cf], bfr, acc[cf][pf], 0, 0, 0);
        }
      }
    }
    __syncthreads();
  }
  unsigned short* outB = out + (size_t)b * NPIX * OST;
#pragma unroll
  for (int cf = 0; cf < COF; ++cf) {
    const int co0 = cf * 16 + lq * 4;
    if (co0 >= CO_REAL) continue;
    const float4 bv = *(const float4*)(biasP + co0);
#pragma unroll
    for (int pf = 0; pf < 2; ++pf) {
      const int pix = wv * 32 + pf * 16 + lm;
      const int gpix = (ty0 + (pix >> 4)) * Ww + tx0 + (pix & 15);
      const f32x4 v = acc[cf][pf];
      ushort4 pk;
      pk.x = f2bf(v[0] + bv.x);
      pk.y = f2bf(v[1] + bv.y);
      pk.z = f2bf(v[2] + bv.z);
      pk.w = f2bf(v[3] + bv.w);
      if (OUT_GS)
        *(ushort4*)(out + ((size_t)(b * 4 + cf) * NPIX + gpix) * 16 + lq * 4) =
            pk;
      else
        *(ushort4*)(outB + (size_t)gpix * OST + co0) = pk;
    }
  }
}

// ---------------------------------------------------------------------------
// MFMA deform v7: 128-thread blocks (2 waves), 8x8 pixel tile, 2 threads per
// pixel (each samples 8 of 16 channels -> 36 gathers/thread). Sampled K=32
// chunks written to LDS (stride 80B) and consumed wave-locally by MFMA
// (pixel p's halves are lanes 2p/2p+1 of the same wave -> no barrier).
// Grid: (256 tiles, G, BB).
// ---------------------------------------------------------------------------
__device__ __forceinline__ float vget8(const u16x8& a, int c) {
  return bf2f((unsigned short)a[c]);
}

template <bool NCHW_OUT>
__global__ __launch_bounds__(128, 6) void deform7_kernel(
    const unsigned short* __restrict__ x,    // [b2][g][pix][16] bf16
    const unsigned short* __restrict__ off,  // [b2][pix][80] bf16
    const unsigned short* __restrict__ dwP,  // [4][5][16][32] bf16
    const float* __restrict__ bias,          // [64]
    float* __restrict__ outF, unsigned short* __restrict__ outH) {
  __shared__ char sB[64 * 80];
  const int tile = blockIdx.x, g = blockIdx.y, b = blockIdx.z;
  const int ty0 = (tile >> 4) << 3, tx0 = (tile & 15) << 3;
  const int tid = threadIdx.x;
  const int p = tid >> 1, h = tid & 1;   // pixel, channel-half
  const int l = tid & 63, wv = tid >> 6;
  const int lm = l & 15, lq = l >> 4;
  const int y = ty0 + (p >> 3), xx = tx0 + (p & 7);

  const unsigned short* xP = x + (size_t)(b * 4 + g) * NPIX * 16 + h * 8;
  const unsigned short* offP =
      off + (size_t)(b * NPIX + y * Ww + xx) * 80 + g * 18;

  // offsets first (longest-latency independent loads)
  unsigned od[9];
#pragma unroll
  for (int t = 0; t < 9; ++t) od[t] = *(const unsigned*)(offP + 2 * t);

  bf16x8 afr[5];
#pragma unroll
  for (int pr = 0; pr < 5; ++pr)
    afr[pr] = *(const bf16x8*)(dwP + ((size_t)(g * 5 + pr) * 16 + lm) * 32 +
                               lq * 8);

  f32x4 acc[2];
  acc[0] = (f32x4){0.f, 0.f, 0.f, 0.f};
  acc[1] = (f32x4){0.f, 0.f, 0.f, 0.f};

  char* myB = sB + p * 80 + h * 16;

#pragma unroll
  for (int pair = 0; pair < 5; ++pair) {
#pragma unroll
    for (int ti = 0; ti < 2; ++ti) {
      const int t = pair * 2 + ti;
      u16x8 sv;
#pragma unroll
      for (int j = 0; j < 8; ++j) sv[j] = 0;
      if (t < 9) {
        const unsigned odw = od[t < 9 ? t : 0];
        const float dy = __uint_as_float(odw << 16);
        const float dx = __uint_as_float(odw & 0xffff0000u);
        const float py = dy + (float)(y - 2 + 2 * (t / 3));
        const float px = dx + (float)(xx - 2 + 2 * (t % 3));
        const float fy = floorf(py), fx = floorf(px);
        const int y0 = (int)fy, x0 = (int)fx;
        const int y1 = y0 + 1, x1 = x0 + 1;
        const float ly = py - fy, lx = px - fx;
        float w00 = (1.f - ly) * (1.f - lx), w01 = (1.f - ly) * lx;
        float w10 = ly * (1.f - lx), w11 = ly * lx;
        const bool vy0 = (y0 >= 0) && (y0 < Hh), vy1 = (y1 >= 0) && (y1 < Hh);
        const bool vx0 = (x0 >= 0) && (x0 < Ww), vx1 = (x1 >= 0) && (x1 < Ww);
        w00 = (vy0 && vx0) ? w00 : 0.f;
        w01 = (vy0 && vx1) ? w01 : 0.f;
        w10 = (vy1 && vx0) ? w10 : 0.f;
        w11 = (vy1 && vx1) ? w11 : 0.f;
        const int y0c = min(max(y0, 0), Hh - 1), y1c = min(max(y1, 0), Hh - 1);
        const int x0c = min(max(x0, 0), Ww - 1), x1c = min(max(x1, 0), Ww - 1);
        const u16x8 a00 = *(const u16x8*)(xP + (size_t)(y0c * Ww + x0c) * 16);
        const u16x8 a01 = *(const u16x8*)(xP + (size_t)(y0c * Ww + x1c) * 16);
        const u16x8 a10 = *(const u16x8*)(xP + (size_t)(y1c * Ww + x0c) * 16);
        const u16x8 a11 = *(const u16x8*)(xP + (size_t)(y1c * Ww + x1c) * 16);
#pragma unroll
        for (int c = 0; c < 8; ++c) {
          const float s = vget8(a00, c) * w00 + vget8(a01, c) * w01 +
                          vget8(a10, c) * w10 + vget8(a11, c) * w11;
          sv[c] = f2bf(s);
        }
      }
      *(u16x8*)(myB + ti * 32) = sv;
    }
    // MFMA over this K=32 chunk (wave-local pixels; no barrier)
#pragma unroll
    for (int n = 0; n < 2; ++n) {
      const bf16x8 bfr =
          *(const bf16x8*)(sB + (wv * 32 + n * 16 + lm) * 80 + lq * 16);
      acc[n] = __builtin_amdgcn_mfma_f32_16x16x32_bf16(afr[pair], bfr, acc[n],
                                                       0, 0, 0);
    }
  }

  // epilogue: +bias; C layout col(pixel)=lm, row(out)=lq*4+r
  const float4 bv = *(const float4*)(bias + g * 16 + lq * 4);
#pragma unroll
  for (int n = 0; n < 2; ++n) {
    const int pixl = wv * 32 + n * 16 + lm;
    const int gpix = (ty0 + (pixl >> 3)) * Ww + tx0 + (pixl & 7);
    const f32x4 v = acc[n];
    if (NCHW_OUT) {
      float* oB = outF + (size_t)(b * 64 + g * 16 + lq * 4) * NPIX + gpix;
      oB[0] = v[0] + bv.x;
      oB[NPIX] = v[1] + bv.y;
      oB[2 * NPIX] = v[2] + bv.z;
      oB[3 * NPIX] = v[3] + bv.w;
    } else {
      ushort4 pk;
      pk.x = f2bf(v[0] + bv.x);
      pk.y = f2bf(v[1] + bv.y);
      pk.z = f2bf(v[2] + bv.z);
      pk.w = f2bf(v[3] + bv.w);
      *(ushort4*)(outH + ((size_t)(b * 4 + g) * NPIX + gpix) * 16 + lq * 4) =
          pk;
    }
  }
}

// ---------------------------------------------------------------------------

extern "C" void kernel_launch(void* const* d_in, const int* in_sizes, int n_in,
                              void* d_out, int out_size, void* d_ws,
                              size_t ws_size, hipStream_t stream) {
  const float* Fref = (const float*)d_in[0];
  const float* Fmov1 = (const float*)d_in[1];
  const float* Fmov2 = (const float*)d_in[2];
  const float* cr_w = (const float*)d_in[3];
  const float* cr_b = (const float*)d_in[4];
  const float* offw[4] = {(const float*)d_in[5], (const float*)d_in[7],
                          (const float*)d_in[9], (const float*)d_in[11]};
  const float* offb[4] = {(const float*)d_in[6], (const float*)d_in[8],
                          (const float*)d_in[10], (const float*)d_in[12]};
  const float* dw[4] = {(const float*)d_in[13], (const float*)d_in[15],
                        (const float*)d_in[17], (const float*)d_in[19]};
  const float* db[4] = {(const float*)d_in[14], (const float*)d_in[16],
                        (const float*)d_in[18], (const float*)d_in[20]};

  char* p = (char*)d_ws;
  auto carve = [&](size_t bytes) {
    void* r = p;
    p += (bytes + 255) & ~(size_t)255;
    return r;
  };
  unsigned short* frefG = (unsigned short*)carve((size_t)4 * 4 * NPIX * 16 * 2);
  unsigned short* fmovG = (unsigned short*)carve((size_t)BB * 4 * NPIX * 16 * 2);
  unsigned short* feaA = (unsigned short*)carve((size_t)BB * 4 * NPIX * 16 * 2);
  unsigned short* feaB = (unsigned short*)carve((size_t)BB * 4 * NPIX * 16 * 2);
  unsigned short* offB = (unsigned short*)carve((size_t)BB * NPIX * 80 * 2);
  unsigned short* wcrT = (unsigned short*)carve((size_t)9 * 64 * 128 * 2);
  unsigned short* woffT[4];
  for (int i = 0; i < 4; ++i)
    woffT[i] = (unsigned short*)carve((size_t)9 * 80 * 64 * 2);
  unsigned short* dwP[4];
  for (int i = 0; i < 4; ++i)
    dwP[i] = (unsigned short*)carve((size_t)4 * 5 * 16 * 32 * 2);

  PrepPtrs pp;
  pp.cw[0] = cr_w;
  pp.cd[0] = wcrT;
  for (int i = 0; i < 4; ++i) {
    pp.cw[i + 1] = offw[i];
    pp.cd[i + 1] = woffT[i];
    pp.dw[i] = dw[i];
    pp.dd[i] = dwP[i];
  }
  prep_all_kernel<<<dim3(288, 9), 256, 0, stream>>>(pp);

  to_gs_kernel<<<BB * NPIX / 256, 256, 0, stream>>>(Fref, Fmov1, Fmov2, frefG,
                                                    fmovG);

  const dim3 cgrid(64, BB), cblk(512);
  const dim3 dgrid(256, 4, BB), dblk(128);
  float* outF = (float*)d_out;  // [b2][64][H][W], b2 0-3 = branch1, 4-7 = br2

  // fea = conv([Fref|Fmov], cr)            -> feaA (GS)
  convmfma_kernel<128, 64, 64, 0, true><<<cgrid, cblk, 0, stream>>>(
      frefG, 3, fmovG, 7, wcrT, cr_b, feaA);
  // off1; fea = deform(feaA, off1, d1)     -> feaB
  convmfma_kernel<64, 80, 72, 80, false><<<cgrid, cblk, 0, stream>>>(
      feaA, 7, nullptr, 0, woffT[0], offb[0], offB);
  deform7_kernel<false>
      <<<dgrid, dblk, 0, stream>>>(feaA, offB, dwP[0], db[0], nullptr, feaB);
  // off2; fea = deform(feaB, off2, d2)     -> feaA
  convmfma_kernel<64, 80, 72, 80, false><<<cgrid, cblk, 0, stream>>>(
      feaB, 7, nullptr, 0, woffT[1], offb[1], offB);
  deform7_kernel<false>
      <<<dgrid, dblk, 0, stream>>>(feaB, offB, dwP[1], db[1], nullptr, feaA);
  // off3 from feaA; fea = deform(fmovG, off3, d3) -> feaB
  convmfma_kernel<64, 80, 72, 80, false><<<cgrid, cblk, 0, stream>>>(
      feaA, 7, nullptr, 0, woffT[2], offb[2], offB);
  deform7_kernel<false>
      <<<dgrid, dblk, 0, stream>>>(fmovG, offB, dwP[2], db[2], nullptr, feaB);
  // off4; out = deform(feaB, off4, d4)     -> d_out (f32 NCHW, b2-indexed)
  convmfma_kernel<64, 80, 72, 80, false><<<cgrid, cblk, 0, stream>>>(
      feaB, 7, nullptr, 0, woffT[3], offb[3], offB);
  deform7_kernel<true>
      <<<dgrid, dblk, 0, stream>>>(feaB, offB, dwP[3], db[3], outF, nullptr);
}